// Round 1
// baseline (3210.157 us; speedup 1.0000x reference)
//
#include <hip/hip_runtime.h>

// Problem constants (fixed by reference)
#define NN 20000          // nodes
#define NEDGE 320000      // edges
#define D 256             // hidden dim
#define RD 512            // router/expert input dim (2*D)
#define OD 128            // output dim
#define NEXP 8            // experts
#define NSLOT (2*NN)      // top-2 assignment slots
#define NODE_BLOCKS 79    // ceil(NN/256)

// ---------------------------------------------------------------------------
// small helper kernels
// ---------------------------------------------------------------------------

// copy x into r[:, :256] (h lives in first half of r), zero edge counts
__global__ void copy_x_zero_cnt_k(const float* __restrict__ x, float* __restrict__ r,
                                  int* __restrict__ cnt) {
    int gid = blockIdx.x * 256 + threadIdx.x;          // 1,280,000 float4 units
    int n = gid >> 6;
    int c4 = gid & 63;
    if (gid < NN * (D / 4)) {
        float4 v = reinterpret_cast<const float4*>(x)[gid];
        reinterpret_cast<float4*>(r + (size_t)n * RD)[c4] = v;
    }
    if (gid < NN) cnt[gid] = 0;
}

__global__ void count_edges_k(const int* __restrict__ dst, int* __restrict__ cnt) {
    int e = blockIdx.x * 256 + threadIdx.x;
    if (e < NEDGE) atomicAdd(&cnt[dst[e]], 1);
}

__global__ void block_sums_k(const int* __restrict__ cnt, int* __restrict__ bsum) {
    __shared__ int s[256];
    int i = blockIdx.x * 256 + threadIdx.x;
    s[threadIdx.x] = (i < NN) ? cnt[i] : 0;
    __syncthreads();
    for (int off = 128; off > 0; off >>= 1) {
        if (threadIdx.x < off) s[threadIdx.x] += s[threadIdx.x + off];
        __syncthreads();
    }
    if (threadIdx.x == 0) bsum[blockIdx.x] = s[0];
}

__global__ void scan_bsums_k(int* __restrict__ bsum, int* __restrict__ row_start) {
    if (blockIdx.x == 0 && threadIdx.x == 0) {
        int acc = 0;
        for (int i = 0; i < NODE_BLOCKS; i++) { int t = bsum[i]; bsum[i] = acc; acc += t; }
        row_start[NN] = acc;   // == NEDGE
    }
}

__global__ void block_scan_k(const int* __restrict__ cnt, const int* __restrict__ bsum,
                             int* __restrict__ row_start, int* __restrict__ cur) {
    __shared__ int s[256];
    int i = blockIdx.x * 256 + threadIdx.x;
    int v = (i < NN) ? cnt[i] : 0;
    s[threadIdx.x] = v;
    __syncthreads();
    for (int off = 1; off < 256; off <<= 1) {
        int t = (threadIdx.x >= off) ? s[threadIdx.x - off] : 0;
        __syncthreads();
        s[threadIdx.x] += t;
        __syncthreads();
    }
    int excl = s[threadIdx.x] - v + bsum[blockIdx.x];
    if (i < NN) { row_start[i] = excl; cur[i] = excl; }
}

__global__ void fill_csr_k(const int* __restrict__ src, const int* __restrict__ dst,
                           int* __restrict__ cur, int* __restrict__ csr_src) {
    int e = blockIdx.x * 256 + threadIdx.x;
    if (e < NEDGE) {
        int pos = atomicAdd(&cur[dst[e]], 1);
        csr_src[pos] = src[e];
    }
}

// mean-aggregate incoming neighbors of h (= r[:, :256]) into r[:, 256:512].
// one wave per node; lane owns 4 contiguous dims (float4). Also zero ec[8].
__global__ void aggregate_k(float* __restrict__ r, const int* __restrict__ row_start,
                            const int* __restrict__ csr_src, int* __restrict__ ec) {
    if (blockIdx.x == 0 && threadIdx.x < 16) ec[threadIdx.x] = 0;
    int wid = blockIdx.x * 4 + (threadIdx.x >> 6);
    int lane = threadIdx.x & 63;
    if (wid >= NN) return;
    int beg = row_start[wid], end = row_start[wid + 1];
    float ax = 0.f, ay = 0.f, az = 0.f, aw = 0.f;
    for (int j = beg; j < end; j++) {
        int s = csr_src[j];
        float4 v = reinterpret_cast<const float4*>(r + (size_t)s * RD)[lane];
        ax += v.x; ay += v.y; az += v.z; aw += v.w;
    }
    float deg = (float)((end - beg) > 1 ? (end - beg) : 1);
    float4 o = make_float4(ax / deg, ay / deg, az / deg, aw / deg);
    reinterpret_cast<float4*>(r + (size_t)wid * RD + D)[lane] = o;
}

// hierarchical router: one wave per node. f32 throughout (routing decisions
// are discontinuous -> must match reference at f32 fidelity).
__global__ void router_k(const float* __restrict__ r, const float* __restrict__ Wg,
                         const float* __restrict__ We, const float* __restrict__ wc,
                         int* __restrict__ node_top, float* __restrict__ node_gate,
                         float* __restrict__ conf, int* __restrict__ ec) {
    int wid = blockIdx.x * 4 + (threadIdx.x >> 6);
    int lane = threadIdx.x & 63;
    if (wid >= NN) return;

    const float* rr = r + (size_t)wid * RD + lane * 8;
    float4 rv0 = *reinterpret_cast<const float4*>(rr);
    float4 rv1 = *reinterpret_cast<const float4*>(rr + 4);
    float rv[8] = {rv0.x, rv0.y, rv0.z, rv0.w, rv1.x, rv1.y, rv1.z, rv1.w};

    float pg[4] = {0, 0, 0, 0};
    float pe[8] = {0, 0, 0, 0, 0, 0, 0, 0};
    float pc = 0.f;
    int kb = lane * 8;
#pragma unroll
    for (int i = 0; i < 8; i++) {
        float rvi = rv[i];
        float4 wg = *reinterpret_cast<const float4*>(Wg + (size_t)(kb + i) * 4);
        pg[0] = fmaf(rvi, wg.x, pg[0]); pg[1] = fmaf(rvi, wg.y, pg[1]);
        pg[2] = fmaf(rvi, wg.z, pg[2]); pg[3] = fmaf(rvi, wg.w, pg[3]);
        float4 w0 = *reinterpret_cast<const float4*>(We + (size_t)(kb + i) * 8);
        float4 w1 = *reinterpret_cast<const float4*>(We + (size_t)(kb + i) * 8 + 4);
        pe[0] = fmaf(rvi, w0.x, pe[0]); pe[1] = fmaf(rvi, w0.y, pe[1]);
        pe[2] = fmaf(rvi, w0.z, pe[2]); pe[3] = fmaf(rvi, w0.w, pe[3]);
        pe[4] = fmaf(rvi, w1.x, pe[4]); pe[5] = fmaf(rvi, w1.y, pe[5]);
        pe[6] = fmaf(rvi, w1.z, pe[6]); pe[7] = fmaf(rvi, w1.w, pe[7]);
        pc = fmaf(rvi, wc[kb + i], pc);
    }
#pragma unroll
    for (int off = 32; off > 0; off >>= 1) {
#pragma unroll
        for (int g = 0; g < 4; g++) pg[g] += __shfl_xor(pg[g], off);
#pragma unroll
        for (int g = 0; g < 8; g++) pe[g] += __shfl_xor(pe[g], off);
        pc += __shfl_xor(pc, off);
    }

    if (lane == 0) {
        float m = fmaxf(fmaxf(pg[0], pg[1]), fmaxf(pg[2], pg[3]));
        float eg[4]; float sg = 0.f;
#pragma unroll
        for (int g = 0; g < 4; g++) { eg[g] = expf(pg[g] - m); sg += eg[g]; }
        float probs[8];
#pragma unroll
        for (int g = 0; g < 4; g++) {
            float a = pe[2 * g], b = pe[2 * g + 1];
            float mm = fmaxf(a, b);
            float ea = expf(a - mm), eb = expf(b - mm);
            float inv = 1.f / (ea + eb);
            float gp = eg[g] / sg;
            probs[2 * g]     = gp * ea * inv;
            probs[2 * g + 1] = gp * eb * inv;
        }
        int i0 = 0; float v0 = probs[0];
#pragma unroll
        for (int j = 1; j < 8; j++) if (probs[j] > v0) { v0 = probs[j]; i0 = j; }
        int i1 = -1; float v1 = -1e30f;
#pragma unroll
        for (int j = 0; j < 8; j++) if (j != i0 && probs[j] > v1) { v1 = probs[j]; i1 = j; }
        float s = v0 + v1 + 1e-9f;
        node_top[2 * wid] = i0;  node_top[2 * wid + 1] = i1;
        node_gate[2 * wid] = v0 / s;  node_gate[2 * wid + 1] = v1 / s;
        conf[wid] = 1.f / (1.f + expf(-pc));
        atomicAdd(&ec[i0], 1);
        atomicAdd(&ec[i1], 1);
    }
}

__global__ void expert_scan_k(const int* __restrict__ ec, int* __restrict__ es,
                              int* __restrict__ ecur) {
    if (blockIdx.x == 0 && threadIdx.x == 0) {
        int acc = 0;
        for (int e = 0; e < NEXP; e++) { es[e] = acc; acc += ec[e]; ecur[e] = 0; }
        es[NEXP] = acc;
    }
}

__global__ void fill_experts_k(const int* __restrict__ node_top, const float* __restrict__ node_gate,
                               const int* __restrict__ es, int* __restrict__ ecur,
                               int* __restrict__ slot_node, float* __restrict__ slot_gate,
                               int* __restrict__ node_slot) {
    int n = blockIdx.x * 256 + threadIdx.x;
    if (n >= NN) return;
#pragma unroll
    for (int j = 0; j < 2; j++) {
        int e = node_top[2 * n + j];
        int pos = atomicAdd(&ecur[e], 1);
        int slot = es[e] + pos;
        slot_node[slot] = n;
        slot_gate[slot] = node_gate[2 * n + j];
        node_slot[2 * n + j] = slot;
    }
}

// h_next = relu(conf*(expout[s0]+expout[s1]) + (1-conf)*weak), written into r[:, :256]
__global__ void combine_k(const float* __restrict__ expout, const float* __restrict__ weak,
                          const float* __restrict__ conf, const int* __restrict__ node_slot,
                          float* __restrict__ r) {
    int gid = blockIdx.x * 256 + threadIdx.x;     // NN*64 float4 units
    if (gid >= NN * (D / 4)) return;
    int n = gid >> 6, c4 = gid & 63;
    int s0 = node_slot[2 * n], s1 = node_slot[2 * n + 1];
    float4 e0 = reinterpret_cast<const float4*>(expout + (size_t)s0 * D)[c4];
    float4 e1 = reinterpret_cast<const float4*>(expout + (size_t)s1 * D)[c4];
    float4 w  = reinterpret_cast<const float4*>(weak + (size_t)n * D)[c4];
    float cf = conf[n], cg = 1.f - cf;
    float4 o;
    o.x = fmaxf(cf * (e0.x + e1.x) + cg * w.x, 0.f);
    o.y = fmaxf(cf * (e0.y + e1.y) + cg * w.y, 0.f);
    o.z = fmaxf(cf * (e0.z + e1.z) + cg * w.z, 0.f);
    o.w = fmaxf(cf * (e0.w + e1.w) + cg * w.w, 0.f);
    reinterpret_cast<float4*>(r + (size_t)n * RD)[c4] = o;
}

// ---------------------------------------------------------------------------
// f32 tiled GEMM: C[M,N] = A[M,K] * B[K,N]  (B in natural [K][N] layout)
// 128x128 tile, BK=16, 256 threads, 8x8 outputs/thread.
// MODE 0: plain, store f32 C (weak GEMM, final GEMM)
// MODE 1: expert-bucketed, A rows gathered via slot_node, +bias, relu -> C[slot]
// MODE 2: expert-bucketed, A rows are slots (hid), +bias, *gate -> C[slot]
// ---------------------------------------------------------------------------
template <int MODE>
__global__ __launch_bounds__(256, 2) void gemm_f32(
    const float* __restrict__ A, int lda,
    const float* __restrict__ B, int ldb,
    const float* __restrict__ bias,
    float* __restrict__ C, int ldc,
    const int* __restrict__ es,
    const int* __restrict__ slot_node,
    const float* __restrict__ slot_gate,
    int M, int N, int K) {
    constexpr int BM = 128, BK = 16, LDM = 132;   // LDM: padded M-stride in LDS
    __shared__ float sA[BK * LDM];
    __shared__ float sB[BK * LDM];

    int tid = threadIdx.x;
    int row0, valid_rows;
    if (MODE == 0) {
        row0 = blockIdx.x * BM;
        valid_rows = M - row0; if (valid_rows > BM) valid_rows = BM;
    } else {
        int bx = blockIdx.x, acc = 0, expert = -1, mt = 0;
        for (int e = 0; e < NEXP; e++) {
            int c = es[e + 1] - es[e];
            int t = (c + BM - 1) / BM;
            if (bx < acc + t) { expert = e; mt = bx - acc; row0 = es[e] + mt * BM;
                                valid_rows = c - mt * BM; if (valid_rows > BM) valid_rows = BM; break; }
            acc += t;
        }
        if (expert < 0) return;           // uniform for whole block
        B += (size_t)expert * K * ldb;
        bias += expert * D;
    }
    int ncol0 = blockIdx.y * BM;

    // staging coordinates
    int sm  = tid >> 2;            // A rows sm, sm+64
    int sk4 = (tid & 3) * 4;       // A k offset within tile
    int skB = tid >> 5;            // B rows skB, skB+8
    int sn4 = (tid & 31) * 4;      // B col offset

    // A row pointers (row gather resolved once)
    bool av0, av1;
    const float *aptr0, *aptr1;
    {
        int r0 = sm, r1 = sm + 64;
        av0 = r0 < valid_rows; av1 = r1 < valid_rows;
        int g0, g1;
        if (MODE == 1) {
            g0 = av0 ? slot_node[row0 + r0] : 0;
            g1 = av1 ? slot_node[row0 + r1] : 0;
        } else {
            g0 = row0 + (av0 ? r0 : 0);
            g1 = row0 + (av1 ? r1 : 0);
        }
        aptr0 = A + (size_t)g0 * lda + sk4;
        aptr1 = A + (size_t)g1 * lda + sk4;
    }
    const float* bptr0 = B + (size_t)skB * ldb + ncol0 + sn4;
    const float* bptr1 = bptr0 + (size_t)8 * ldb;

    float acc[2][2][4][4] = {};
    int ty4 = (tid >> 4) * 4;
    int tx4 = (tid & 15) * 4;

    for (int k0 = 0; k0 < K; k0 += BK) {
        float4 a0 = av0 ? *reinterpret_cast<const float4*>(aptr0 + k0) : make_float4(0, 0, 0, 0);
        float4 a1 = av1 ? *reinterpret_cast<const float4*>(aptr1 + k0) : make_float4(0, 0, 0, 0);
        float4 b0 = *reinterpret_cast<const float4*>(bptr0 + (size_t)k0 * ldb);
        float4 b1 = *reinterpret_cast<const float4*>(bptr1 + (size_t)k0 * ldb);
        __syncthreads();
        // A transposed into sA[k][m]
        sA[(sk4 + 0) * LDM + sm] = a0.x;
        sA[(sk4 + 1) * LDM + sm] = a0.y;
        sA[(sk4 + 2) * LDM + sm] = a0.z;
        sA[(sk4 + 3) * LDM + sm] = a0.w;
        sA[(sk4 + 0) * LDM + sm + 64] = a1.x;
        sA[(sk4 + 1) * LDM + sm + 64] = a1.y;
        sA[(sk4 + 2) * LDM + sm + 64] = a1.z;
        sA[(sk4 + 3) * LDM + sm + 64] = a1.w;
        // B natural into sB[k][n]
        *reinterpret_cast<float4*>(&sB[skB * LDM + sn4]) = b0;
        *reinterpret_cast<float4*>(&sB[(skB + 8) * LDM + sn4]) = b1;
        __syncthreads();
#pragma unroll
        for (int k = 0; k < BK; k++) {
            float4 alo = *reinterpret_cast<const float4*>(&sA[k * LDM + ty4]);
            float4 ahi = *reinterpret_cast<const float4*>(&sA[k * LDM + 64 + ty4]);
            float4 blo = *reinterpret_cast<const float4*>(&sB[k * LDM + tx4]);
            float4 bhi = *reinterpret_cast<const float4*>(&sB[k * LDM + 64 + tx4]);
            float al[4] = {alo.x, alo.y, alo.z, alo.w};
            float ah[4] = {ahi.x, ahi.y, ahi.z, ahi.w};
            float bl[4] = {blo.x, blo.y, blo.z, blo.w};
            float bh[4] = {bhi.x, bhi.y, bhi.z, bhi.w};
#pragma unroll
            for (int i = 0; i < 4; i++)
#pragma unroll
                for (int j = 0; j < 4; j++) {
                    acc[0][0][i][j] = fmaf(al[i], bl[j], acc[0][0][i][j]);
                    acc[0][1][i][j] = fmaf(al[i], bh[j], acc[0][1][i][j]);
                    acc[1][0][i][j] = fmaf(ah[i], bl[j], acc[1][0][i][j]);
                    acc[1][1][i][j] = fmaf(ah[i], bh[j], acc[1][1][i][j]);
                }
        }
    }

    // epilogue
#pragma unroll
    for (int ri = 0; ri < 2; ri++) {
#pragma unroll
        for (int i = 0; i < 4; i++) {
            int lr = ri * 64 + ty4 + i;
            if (lr >= valid_rows) continue;
#pragma unroll
            for (int ci = 0; ci < 2; ci++) {
                int cb = ncol0 + ci * 64 + tx4;
                float4 v = make_float4(acc[ri][ci][i][0], acc[ri][ci][i][1],
                                       acc[ri][ci][i][2], acc[ri][ci][i][3]);
                if (MODE == 0) {
                    int gr = row0 + lr;
                    *reinterpret_cast<float4*>(&C[(size_t)gr * ldc + cb]) = v;
                } else if (MODE == 1) {
                    int slot = row0 + lr;
                    v.x = fmaxf(v.x + bias[cb + 0], 0.f);
                    v.y = fmaxf(v.y + bias[cb + 1], 0.f);
                    v.z = fmaxf(v.z + bias[cb + 2], 0.f);
                    v.w = fmaxf(v.w + bias[cb + 3], 0.f);
                    *reinterpret_cast<float4*>(&C[(size_t)slot * ldc + cb]) = v;
                } else {
                    int slot = row0 + lr;
                    float g = slot_gate[slot];
                    v.x = (v.x + bias[cb + 0]) * g;
                    v.y = (v.y + bias[cb + 1]) * g;
                    v.z = (v.z + bias[cb + 2]) * g;
                    v.w = (v.w + bias[cb + 3]) * g;
                    *reinterpret_cast<float4*>(&C[(size_t)slot * ldc + cb]) = v;
                }
            }
        }
    }
}

// ---------------------------------------------------------------------------
extern "C" void kernel_launch(void* const* d_in, const int* in_sizes, int n_in,
                              void* d_out, int out_size, void* d_ws, size_t ws_size,
                              hipStream_t stream) {
    (void)in_sizes; (void)n_in; (void)out_size; (void)ws_size;
    const float* x    = (const float*)d_in[0];
    const int*   ei   = (const int*)d_in[1];
    const float* Wg   = (const float*)d_in[2];
    const float* We   = (const float*)d_in[3];
    const float* Ww   = (const float*)d_in[4];
    const float* W1   = (const float*)d_in[5];
    const float* b1   = (const float*)d_in[6];
    const float* W2   = (const float*)d_in[7];
    const float* b2   = (const float*)d_in[8];
    const float* wc   = (const float*)d_in[9];
    const float* Wout = (const float*)d_in[10];
    float* out = (float*)d_out;

    char* p = (char*)d_ws;
    auto alloc = [&](size_t bytes) -> char* {
        char* q = p; p += (bytes + 255) & ~(size_t)255; return q;
    };
    int*   cnt       = (int*)alloc((size_t)NN * 4);
    int*   row_start = (int*)alloc((size_t)(NN + 1) * 4);
    int*   cur       = (int*)alloc((size_t)NN * 4);
    int*   bsum      = (int*)alloc(128 * 4);
    int*   csr_src   = (int*)alloc((size_t)NEDGE * 4);
    float* r         = (float*)alloc((size_t)NN * RD * 4);
    float* hid       = (float*)alloc((size_t)NSLOT * D * 4);
    float* expout    = (float*)alloc((size_t)NSLOT * D * 4);
    float* weak      = (float*)alloc((size_t)NN * D * 4);
    float* conf      = (float*)alloc((size_t)NN * 4);
    int*   node_top  = (int*)alloc((size_t)2 * NN * 4);
    float* node_gate = (float*)alloc((size_t)2 * NN * 4);
    int*   node_slot = (int*)alloc((size_t)2 * NN * 4);
    int*   slot_node = (int*)alloc((size_t)NSLOT * 4);
    float* slot_gate = (float*)alloc((size_t)NSLOT * 4);
    int*   ec        = (int*)alloc(64 * 4);
    int*   es        = (int*)alloc(64 * 4);
    int*   ecur      = (int*)alloc(64 * 4);

    const int* srcp = ei;
    const int* dstp = ei + NEDGE;
    const int EB = (NEDGE + 255) / 256;

    // graph prep (once per launch)
    copy_x_zero_cnt_k<<<5000, 256, 0, stream>>>(x, r, cnt);
    count_edges_k<<<EB, 256, 0, stream>>>(dstp, cnt);
    block_sums_k<<<NODE_BLOCKS, 256, 0, stream>>>(cnt, bsum);
    scan_bsums_k<<<1, 64, 0, stream>>>(bsum, row_start);
    block_scan_k<<<NODE_BLOCKS, 256, 0, stream>>>(cnt, bsum, row_start, cur);
    fill_csr_k<<<EB, 256, 0, stream>>>(srcp, dstp, cur, csr_src);

    dim3 g_weak(157, 2), g_exp(320, 2), g_fin(157, 1);
    for (int l = 0; l < 3; l++) {
        aggregate_k<<<5000, 256, 0, stream>>>(r, row_start, csr_src, ec);
        router_k<<<5000, 256, 0, stream>>>(r,
            Wg + (size_t)l * RD * 4, We + (size_t)l * RD * 8, wc + (size_t)l * RD,
            node_top, node_gate, conf, ec);
        expert_scan_k<<<1, 64, 0, stream>>>(ec, es, ecur);
        fill_experts_k<<<NODE_BLOCKS, 256, 0, stream>>>(node_top, node_gate, es, ecur,
                                                        slot_node, slot_gate, node_slot);
        // weak = r @ Ww[l]
        gemm_f32<0><<<g_weak, 256, 0, stream>>>(r, RD, Ww + (size_t)l * RD * D, D,
                                                nullptr, weak, D,
                                                nullptr, nullptr, nullptr, NN, D, RD);
        // hid[slot] = relu(r[node] @ W1[l][e] + b1[l][e])
        gemm_f32<1><<<g_exp, 256, 0, stream>>>(r, RD, W1 + (size_t)l * NEXP * RD * D, D,
                                               b1 + (size_t)l * NEXP * D, hid, D,
                                               es, slot_node, slot_gate, 0, D, RD);
        // expout[slot] = (hid[slot] @ W2[l][e] + b2[l][e]) * gate[slot]
        gemm_f32<2><<<g_exp, 256, 0, stream>>>(hid, D, W2 + (size_t)l * NEXP * D * D, D,
                                               b2 + (size_t)l * NEXP * D, expout, D,
                                               es, slot_node, slot_gate, 0, D, D);
        combine_k<<<5000, 256, 0, stream>>>(expout, weak, conf, node_slot, r);
    }
    // out = h @ Wout
    gemm_f32<0><<<g_fin, 256, 0, stream>>>(r, RD, Wout, OD, nullptr, out, OD,
                                           nullptr, nullptr, nullptr, NN, OD, D);
}